// Round 16
// baseline (178.989 us; speedup 1.0000x reference)
//
#include <hip/hip_runtime.h>
#include <stdint.h>

#define LEAKY(x) fmaxf((x), 0.2f * (x))

typedef short bf16x8 __attribute__((ext_vector_type(8)));
typedef float f32x4 __attribute__((ext_vector_type(4)));

__device__ inline float2 bf2_to_f2(uint32_t p) {
    return make_float2(__uint_as_float(p << 16), __uint_as_float(p & 0xffff0000u));
}
__device__ inline uint32_t pack_bf2(float x, float y) {
    uint32_t xb = __float_as_uint(x), yb = __float_as_uint(y);
    xb += 0x7fff + ((xb >> 16) & 1);   // RNE to bf16
    yb += 0x7fff + ((yb >> 16) & 1);
    return (xb >> 16) | (yb & 0xffff0000u);
}
__device__ inline ushort to_bf16(float v) {
    uint32_t b = __float_as_uint(v);
    b += 0x7fff + ((b >> 16) & 1);
    return (ushort)(b >> 16);
}

// ------- CSR degree + (independent) W1 transpose fused into one launch -------

__global__ __launch_bounds__(256) void degree_w1t_kernel(const int* __restrict__ dst,
                                                         int* __restrict__ deg, int E,
                                                         int nEb,
                                                         const float* __restrict__ W,
                                                         ushort* __restrict__ WT) {
    if ((int)blockIdx.x < nEb) {
        int e = blockIdx.x * 256 + threadIdx.x;
        if (e < E) atomicAdd(&deg[dst[e]], 1);
    } else {
        int bb = blockIdx.x - nEb;                 // 0..7
        int c = bb * 64 + (threadIdx.x & 63);
        int k0 = (threadIdx.x >> 6) * 32;
        #pragma unroll
        for (int j = 0; j < 32; ++j)
            WT[(size_t)c * 128 + k0 + j] = to_bf16(W[(size_t)(k0 + j) * 512 + c]);
    }
}

// Hierarchical exclusive scan: 13 blocks x 4096 elems -> top scan -> add base.
// scan3 also emits `cur` (a second copy of off) used as the scatter cursor.

__global__ __launch_bounds__(1024) void scan1_kernel(const int* __restrict__ deg,
                                                     int* __restrict__ off,
                                                     int* __restrict__ bsum, int n) {
    __shared__ int wsum[16];
    int b = blockIdx.x, tid = threadIdx.x;
    int lane = tid & 63, wid = tid >> 6;
    int i0 = b * 4096 + tid * 4;
    int v0 = 0, v1 = 0, v2 = 0, v3 = 0;
    if (i0 + 3 < n) {
        int4 q = *(const int4*)(deg + i0);
        v0 = q.x; v1 = q.y; v2 = q.z; v3 = q.w;
    } else {
        if (i0 + 0 < n) v0 = deg[i0];
        if (i0 + 1 < n) v1 = deg[i0 + 1];
        if (i0 + 2 < n) v2 = deg[i0 + 2];
        if (i0 + 3 < n) v3 = deg[i0 + 3];
    }
    int s = v0 + v1 + v2 + v3;
    int x = s;
    #pragma unroll
    for (int d2 = 1; d2 < 64; d2 <<= 1) {
        int y = __shfl_up(x, d2);
        if (lane >= d2) x += y;
    }
    if (lane == 63) wsum[wid] = x;
    __syncthreads();
    if (tid < 16) {
        int t = wsum[tid];
        #pragma unroll
        for (int d2 = 1; d2 < 16; d2 <<= 1) {
            int y = __shfl_up(t, d2, 16);
            if (tid >= d2) t += y;
        }
        wsum[tid] = t;
    }
    __syncthreads();
    int wbase = wid ? wsum[wid - 1] : 0;
    int pre = wbase + (x - s);                 // exclusive prefix within block
    if (i0 < n)     off[i0]     = pre;
    if (i0 + 1 < n) off[i0 + 1] = pre + v0;
    if (i0 + 2 < n) off[i0 + 2] = pre + v0 + v1;
    if (i0 + 3 < n) off[i0 + 3] = pre + v0 + v1 + v2;
    if (tid == 0) bsum[b] = wsum[15];          // block total
}

__global__ void scan2_kernel(int* __restrict__ bsum, int* __restrict__ off, int nb, int n) {
    int tid = threadIdx.x;  // 64 threads, nb <= 64
    int v = (tid < nb) ? bsum[tid] : 0;
    int x = v;
    #pragma unroll
    for (int d2 = 1; d2 < 64; d2 <<= 1) {
        int y = __shfl_up(x, d2);
        if (tid >= d2) x += y;
    }
    if (tid < nb) bsum[tid] = x - v;           // exclusive block base
    if (tid == 63) off[n] = x;                 // grand total
}

__global__ __launch_bounds__(1024) void scan3_kernel(int* __restrict__ off,
                                                     int* __restrict__ cur,
                                                     const int* __restrict__ bsum, int n) {
    int b = blockIdx.x;
    int base = bsum[b];
    int i = b * 4096 + threadIdx.x * 4;
    if (i + 3 < n) {
        int4 q = *(int4*)(off + i);
        q.x += base; q.y += base; q.z += base; q.w += base;
        *(int4*)(off + i) = q;
        *(int4*)(cur + i) = q;
    } else {
        #pragma unroll
        for (int k = 0; k < 4; ++k)
            if (i + k < n) {
                int v = off[i + k] + base;
                off[i + k] = v;
                cur[i + k] = v;
            }
    }
}

// ------- scatter (CSR fill) and gemm1 fused into one launch (independent work) -------
// Blocks [0, nGb): gemm1 row-blocks. Blocks [nGb, nGb+nEb): scatter.
// gemm1: h1 = x @ W1 via MFMA + fused alpha dots; A staged once, B tiles restaged
// per col-block (L2/L3-resident). T2 swizzle on LDS granules.

__global__ __launch_bounds__(256) void gemm1_scatter_kernel(
        const float* __restrict__ x, const ushort* __restrict__ W1T,
        const float* __restrict__ a_src, const float* __restrict__ a_dst,
        uint32_t* __restrict__ h1, float* __restrict__ asrc1,
        float* __restrict__ adst1, int N, int nGb,
        const int* __restrict__ esrc, const int* __restrict__ edst,
        int* __restrict__ cur, int* __restrict__ csr_src, int E) {
    __shared__ __align__(16) ushort As[128][128];
    __shared__ __align__(16) ushort Bs[128][128];
    int tid = threadIdx.x;
    if ((int)blockIdx.x >= nGb) {   // ---- scatter branch (no barriers touched) ----
        int e = (blockIdx.x - nGb) * 256 + tid;
        if (e < E) {
            int d = edst[e];
            int p = atomicAdd(&cur[d], 1);
            csr_src[p] = esrc[e];
        }
        return;
    }
    int row0 = blockIdx.x * 128;

    {   // stage A (fp32 x -> bf16), swizzled — once
        int g = tid & 15;
        int r4 = tid >> 4;
        #pragma unroll
        for (int pass = 0; pass < 8; ++pass) {
            int r = r4 + pass * 16;
            int gr = row0 + r;
            float4 v0 = make_float4(0.f, 0.f, 0.f, 0.f), v1 = v0;
            if (gr < N) {
                v0 = *(const float4*)(x + (size_t)gr * 128 + g * 8);
                v1 = *(const float4*)(x + (size_t)gr * 128 + g * 8 + 4);
            }
            uint4 pk = make_uint4(pack_bf2(v0.x, v0.y), pack_bf2(v0.z, v0.w),
                                  pack_bf2(v1.x, v1.y), pack_bf2(v1.z, v1.w));
            *(uint4*)&As[r][(g ^ (r & 7)) * 8] = pk;
        }
    }
    __syncthreads();

    int wave = tid >> 6, lane = tid & 63;
    int wr = wave >> 1, wc = wave & 1;
    int lg = lane >> 4, lr = lane & 15;

    for (int cb = 0; cb < 4; ++cb) {
        int c0 = cb * 128;
        {   // stage B tile for this col-block
            int g = tid & 15;
            int r4 = tid >> 4;
            #pragma unroll
            for (int pass = 0; pass < 8; ++pass) {
                int r = r4 + pass * 16;
                uint4 q = *(const uint4*)(W1T + (size_t)(c0 + r) * 128 + g * 8);
                *(uint4*)&Bs[r][(g ^ (r & 7)) * 8] = q;
            }
        }
        __syncthreads();

        f32x4 acc[4][4] = {};
        #pragma unroll
        for (int kk = 0; kk < 4; ++kk) {
            bf16x8 a[4], b[4];
            int gk = kk * 4 + lg;
            #pragma unroll
            for (int mi = 0; mi < 4; ++mi) {
                int r = wr * 64 + mi * 16 + lr;
                a[mi] = *(const bf16x8*)&As[r][(gk ^ (r & 7)) * 8];
            }
            #pragma unroll
            for (int nj = 0; nj < 4; ++nj) {
                int r = wc * 64 + nj * 16 + lr;
                b[nj] = *(const bf16x8*)&Bs[r][(gk ^ (r & 7)) * 8];
            }
            #pragma unroll
            for (int mi = 0; mi < 4; ++mi)
                #pragma unroll
                for (int nj = 0; nj < 4; ++nj)
                    acc[mi][nj] = __builtin_amdgcn_mfma_f32_16x16x32_bf16(
                        a[mi], b[nj], acc[mi][nj], 0, 0, 0);
        }

        // ---- epilogue: alpha dots + bf16 pack. D mapping: col=lr, row=lg*4+reg.
        int hh = cb * 2 + wc;  // head for this wave's 64 cols
        float as4[4], ad4[4];
        #pragma unroll
        for (int nj = 0; nj < 4; ++nj) {
            as4[nj] = a_src[hh * 64 + nj * 16 + lr];
            ad4[nj] = a_dst[hh * 64 + nj * 16 + lr];
        }
        #pragma unroll
        for (int mi = 0; mi < 4; ++mi) {
            #pragma unroll
            for (int reg = 0; reg < 4; ++reg) {
                int row = row0 + wr * 64 + mi * 16 + lg * 4 + reg;
                float v0 = acc[mi][0][reg], v1 = acc[mi][1][reg];
                float v2 = acc[mi][2][reg], v3 = acc[mi][3][reg];
                float ps = v0 * as4[0] + v1 * as4[1] + v2 * as4[2] + v3 * as4[3];
                float pd = v0 * ad4[0] + v1 * ad4[1] + v2 * ad4[2] + v3 * ad4[3];
                #pragma unroll
                for (int m = 1; m < 16; m <<= 1) {
                    ps += __shfl_xor(ps, m);
                    pd += __shfl_xor(pd, m);
                }
                bool store_row = (row < N);
                if (store_row && lr == 0) {
                    asrc1[(size_t)row * 8 + hh] = ps;
                    adst1[(size_t)row * 8 + hh] = pd;
                }
                float p0 = __shfl_xor(v0, 1), p1 = __shfl_xor(v1, 1);
                float p2 = __shfl_xor(v2, 1), p3 = __shfl_xor(v3, 1);
                if (store_row && (lr & 1) == 0) {
                    size_t base = (size_t)row * 256 + ((c0 + wc * 64 + lr) >> 1);
                    h1[base + 0]  = pack_bf2(v0, p0);
                    h1[base + 8]  = pack_bf2(v1, p1);
                    h1[base + 16] = pack_bf2(v2, p2);
                    h1[base + 24] = pack_bf2(v3, p3);
                }
            }
        }
        __syncthreads();   // all waves done with Bs before restaging
    }
}

// ------- Fused layer-1 aggregation + layer-2 GEMM + alpha2 (one wave per node) -------
// Lane l owns contiguous channels [8l, 8l+8) (head = l>>3). W2 staged in LDS [64][68].

__global__ __launch_bounds__(256) void agg1_fused_kernel(
        const uint4* __restrict__ h1, const float* __restrict__ asrc,
        const float* __restrict__ adst, const int* __restrict__ off,
        const int* __restrict__ csr_src, const float* __restrict__ b1,
        const float* __restrict__ W2, const float* __restrict__ a_src2,
        const float* __restrict__ a_dst2, float* __restrict__ h2,
        float* __restrict__ as2, float* __restrict__ ad2, int N) {
    __shared__ __align__(16) float w2s[64 * 68];
    int tid = threadIdx.x;
    #pragma unroll
    for (int q = 0; q < 4; ++q) {
        float4 v = ((const float4*)W2)[tid * 4 + q];
        int g = tid * 16 + q * 4;               // global float index
        *(float4*)&w2s[(g >> 6) * 68 + (g & 63)] = v;
    }
    __syncthreads();

    int n = (blockIdx.x * blockDim.x + tid) >> 6;
    int lane = tid & 63;
    if (n >= N) return;  // after barrier: safe
    int hd = lane >> 3;
    float ad = adst[(size_t)n * 8 + hd];
    float2 acc2[4];
    float d;
    {   // self loop
        float w = __expf(LEAKY(asrc[(size_t)n * 8 + hd] + ad));
        d = w;
        uint4 p = h1[(size_t)n * 64 + lane];
        float2 c0 = bf2_to_f2(p.x), c1 = bf2_to_f2(p.y);
        float2 c2 = bf2_to_f2(p.z), c3 = bf2_to_f2(p.w);
        acc2[0] = make_float2(w * c0.x, w * c0.y);
        acc2[1] = make_float2(w * c1.x, w * c1.y);
        acc2[2] = make_float2(w * c2.x, w * c2.y);
        acc2[3] = make_float2(w * c3.x, w * c3.y);
    }
    auto addp = [&](uint4 p, float w) {
        float2 c0 = bf2_to_f2(p.x), c1 = bf2_to_f2(p.y);
        float2 c2 = bf2_to_f2(p.z), c3 = bf2_to_f2(p.w);
        d += w;
        acc2[0].x += w * c0.x; acc2[0].y += w * c0.y;
        acc2[1].x += w * c1.x; acc2[1].y += w * c1.y;
        acc2[2].x += w * c2.x; acc2[2].y += w * c2.y;
        acc2[3].x += w * c3.x; acc2[3].y += w * c3.y;
    };
    int t = off[n], tend = off[n + 1];
    for (; t + 3 < tend; t += 4) {
        int s0 = csr_src[t], s1 = csr_src[t + 1];
        int s2 = csr_src[t + 2], s3 = csr_src[t + 3];
        uint4 p0 = h1[(size_t)s0 * 64 + lane];
        uint4 p1 = h1[(size_t)s1 * 64 + lane];
        uint4 p2 = h1[(size_t)s2 * 64 + lane];
        uint4 p3 = h1[(size_t)s3 * 64 + lane];
        float w0 = __expf(LEAKY(asrc[(size_t)s0 * 8 + hd] + ad));
        float w1 = __expf(LEAKY(asrc[(size_t)s1 * 8 + hd] + ad));
        float w2 = __expf(LEAKY(asrc[(size_t)s2 * 8 + hd] + ad));
        float w3 = __expf(LEAKY(asrc[(size_t)s3 * 8 + hd] + ad));
        addp(p0, w0); addp(p1, w1); addp(p2, w2); addp(p3, w3);
    }
    for (; t < tend; ++t) {
        int s = csr_src[t];
        uint4 p = h1[(size_t)s * 64 + lane];
        float w = __expf(LEAKY(asrc[(size_t)s * 8 + hd] + ad));
        addp(p, w);
    }
    float inv = 1.f / (d + 1e-16f);
    float4 b0 = *(const float4*)(b1 + lane * 8);
    float4 b4 = *(const float4*)(b1 + lane * 8 + 4);
    float o[8];
    o[0] = fmaxf(acc2[0].x * inv + b0.x, 0.f);
    o[1] = fmaxf(acc2[0].y * inv + b0.y, 0.f);
    o[2] = fmaxf(acc2[1].x * inv + b0.z, 0.f);
    o[3] = fmaxf(acc2[1].y * inv + b0.w, 0.f);
    o[4] = fmaxf(acc2[2].x * inv + b4.x, 0.f);
    o[5] = fmaxf(acc2[2].y * inv + b4.y, 0.f);
    o[6] = fmaxf(acc2[3].x * inv + b4.z, 0.f);
    o[7] = fmaxf(acc2[3].y * inv + b4.w, 0.f);
    asm volatile("" ::: "memory");
    const float* wrow = &w2s[lane * 68];
    float pc[8] = {};
    #pragma unroll
    for (int j = 0; j < 8; ++j) {
        float4 wa = *(const float4*)(wrow + j * 8);
        float4 wb = *(const float4*)(wrow + j * 8 + 4);
        float ov = o[j];
        pc[0] += ov * wa.x; pc[1] += ov * wa.y;
        pc[2] += ov * wa.z; pc[3] += ov * wa.w;
        pc[4] += ov * wb.x; pc[5] += ov * wb.y;
        pc[6] += ov * wb.z; pc[7] += ov * wb.w;
    }
    #pragma unroll
    for (int m = 1; m < 64; m <<= 1)
        #pragma unroll
        for (int c = 0; c < 8; ++c)
            pc[c] += __shfl_xor(pc[c], m);
    if (lane < 8) {
        float myv = 0.f;
        #pragma unroll
        for (int c = 0; c < 8; ++c) if (lane == c) myv = pc[c];
        h2[(size_t)n * 8 + lane] = myv;
        if (lane == 0) {
            float pa = 0.f, pb = 0.f;
            #pragma unroll
            for (int c = 0; c < 8; ++c) { pa += pc[c] * a_src2[c]; pb += pc[c] * a_dst2[c]; }
            as2[n] = pa;
            ad2[n] = pb;
        }
    }
}

// ------- Layer 2 aggregation: one WAVE per node, 8 edges in flight -------
// lane = (e8 = lane>>3 edge slot, c = lane&7 channel). csr_src/as2 reads become
// 8-lane broadcasts; h2 reads 32B-coherent; 3-step shfl_xor (8/16/32) reduces slots.

__global__ __launch_bounds__(256) void agg2_kernel(const float* __restrict__ h2,
                                                   const float* __restrict__ as2,
                                                   const float* __restrict__ ad2,
                                                   const int* __restrict__ off,
                                                   const int* __restrict__ csr_src,
                                                   const float* __restrict__ b2,
                                                   float* __restrict__ out, int N) {
    int n = (blockIdx.x * blockDim.x + threadIdx.x) >> 6;
    if (n >= N) return;
    int lane = threadIdx.x & 63;
    int e8 = lane >> 3, c = lane & 7;
    float adn = ad2[n];
    float d = 0.f, acc = 0.f;
    if (e8 == 0) {   // self loop in slot 0
        float w = __expf(LEAKY(as2[n] + adn));
        d = w;
        acc = w * h2[(size_t)n * 8 + c];
    }
    int tend = off[n + 1];
    for (int t = off[n] + e8; t < tend; t += 8) {
        int s = csr_src[t];
        float w = __expf(LEAKY(as2[s] + adn));
        d += w;
        acc += w * h2[(size_t)s * 8 + c];
    }
    #pragma unroll
    for (int m = 8; m < 64; m <<= 1) {
        d += __shfl_xor(d, m);
        acc += __shfl_xor(acc, m);
    }
    if (lane < 8)
        out[(size_t)n * 8 + c] = acc / (d + 1e-16f) + b2[c];
}

// ---------------- launcher ----------------

extern "C" void kernel_launch(void* const* d_in, const int* in_sizes, int n_in,
                              void* d_out, int out_size, void* d_ws, size_t ws_size,
                              hipStream_t stream) {
    const float* x      = (const float*)d_in[0];
    const int*   ei     = (const int*)d_in[1];
    const float* W1     = (const float*)d_in[2];
    const float* a_src1 = (const float*)d_in[3];
    const float* a_dst1 = (const float*)d_in[4];
    const float* b1     = (const float*)d_in[5];
    const float* W2     = (const float*)d_in[6];
    const float* a_src2 = (const float*)d_in[7];
    const float* a_dst2 = (const float*)d_in[8];
    const float* b2     = (const float*)d_in[9];

    int N = in_sizes[0] / 128;
    int E = in_sizes[1] / 2;
    const int* src = ei;
    const int* dst = ei + E;

    char* w = (char*)d_ws;
    size_t o = 0;
    auto alloc = [&](size_t bytes) {
        void* p = w + o;
        o = (o + bytes + 255) & ~(size_t)255;
        return p;
    };
    uint32_t* h1     = (uint32_t*)alloc((size_t)N * 256 * 4);  // bf16 [N,512]
    float*    asrc1  = (float*)alloc((size_t)N * 8 * 4);
    float*    adst1  = (float*)alloc((size_t)N * 8 * 4);
    float*    h2     = (float*)alloc((size_t)N * 8 * 4);
    float*    as2    = (float*)alloc((size_t)N * 4);
    float*    ad2    = (float*)alloc((size_t)N * 4);
    int*      deg    = (int*)alloc((size_t)N * 4);
    int*      offb   = (int*)alloc((size_t)(N + 1) * 4);
    int*      cur    = (int*)alloc((size_t)N * 4);
    int*      csrs   = (int*)alloc((size_t)E * 4);
    ushort*   W1T    = (ushort*)alloc((size_t)512 * 128 * 2);
    int*      bsum   = (int*)alloc(64 * 4);

    hipMemsetAsync(deg, 0, (size_t)N * 4, stream);

    int nb = (N + 4095) / 4096;
    int nEb = (E + 255) / 256;
    int nGb = (N + 127) / 128;
    degree_w1t_kernel<<<nEb + 8, 256, 0, stream>>>(dst, deg, E, nEb, W1, W1T);
    scan1_kernel<<<nb, 1024, 0, stream>>>(deg, offb, bsum, N);
    scan2_kernel<<<1, 64, 0, stream>>>(bsum, offb, nb, N);
    scan3_kernel<<<nb, 1024, 0, stream>>>(offb, cur, bsum, N);

    gemm1_scatter_kernel<<<nGb + nEb, 256, 0, stream>>>(
        x, W1T, a_src1, a_dst1, h1, asrc1, adst1, N, nGb,
        src, dst, cur, csrs, E);

    agg1_fused_kernel<<<((size_t)N * 64 + 255) / 256, 256, 0, stream>>>(
        (const uint4*)h1, asrc1, adst1, offb, csrs, b1, W2, a_src2, a_dst2,
        h2, as2, ad2, N);

    agg2_kernel<<<((size_t)N * 64 + 255) / 256, 256, 0, stream>>>(h2, as2, ad2, offb, csrs, b2,
                                                                  (float*)d_out, N);
}

// Round 17
// 170.227 us; speedup vs baseline: 1.0515x; 1.0515x over previous
//
#include <hip/hip_runtime.h>
#include <stdint.h>

#define LEAKY(x) fmaxf((x), 0.2f * (x))

typedef short bf16x8 __attribute__((ext_vector_type(8)));
typedef float f32x4 __attribute__((ext_vector_type(4)));

__device__ inline float2 bf2_to_f2(uint32_t p) {
    return make_float2(__uint_as_float(p << 16), __uint_as_float(p & 0xffff0000u));
}
__device__ inline uint32_t pack_bf2(float x, float y) {
    uint32_t xb = __float_as_uint(x), yb = __float_as_uint(y);
    xb += 0x7fff + ((xb >> 16) & 1);   // RNE to bf16
    yb += 0x7fff + ((yb >> 16) & 1);
    return (xb >> 16) | (yb & 0xffff0000u);
}
__device__ inline ushort to_bf16(float v) {
    uint32_t b = __float_as_uint(v);
    b += 0x7fff + ((b >> 16) & 1);
    return (ushort)(b >> 16);
}

// ------- CSR degree + (independent) W1 transpose fused into one launch -------

__global__ __launch_bounds__(256) void degree_w1t_kernel(const int* __restrict__ dst,
                                                         int* __restrict__ deg, int E,
                                                         int nEb,
                                                         const float* __restrict__ W,
                                                         ushort* __restrict__ WT) {
    if ((int)blockIdx.x < nEb) {
        int e = blockIdx.x * 256 + threadIdx.x;
        if (e < E) atomicAdd(&deg[dst[e]], 1);
    } else {
        int bb = blockIdx.x - nEb;                 // 0..7
        int c = bb * 64 + (threadIdx.x & 63);
        int k0 = (threadIdx.x >> 6) * 32;
        #pragma unroll
        for (int j = 0; j < 32; ++j)
            WT[(size_t)c * 128 + k0 + j] = to_bf16(W[(size_t)(k0 + j) * 512 + c]);
    }
}

// Hierarchical exclusive scan: scan1 (per-block) -> scan3 (adds base computed
// from bsum inline; nb <= 13 so the per-block prefix is a trivial scalar loop).

__global__ __launch_bounds__(1024) void scan1_kernel(const int* __restrict__ deg,
                                                     int* __restrict__ off,
                                                     int* __restrict__ bsum, int n) {
    __shared__ int wsum[16];
    int b = blockIdx.x, tid = threadIdx.x;
    int lane = tid & 63, wid = tid >> 6;
    int i0 = b * 4096 + tid * 4;
    int v0 = 0, v1 = 0, v2 = 0, v3 = 0;
    if (i0 + 3 < n) {
        int4 q = *(const int4*)(deg + i0);
        v0 = q.x; v1 = q.y; v2 = q.z; v3 = q.w;
    } else {
        if (i0 + 0 < n) v0 = deg[i0];
        if (i0 + 1 < n) v1 = deg[i0 + 1];
        if (i0 + 2 < n) v2 = deg[i0 + 2];
        if (i0 + 3 < n) v3 = deg[i0 + 3];
    }
    int s = v0 + v1 + v2 + v3;
    int x = s;
    #pragma unroll
    for (int d2 = 1; d2 < 64; d2 <<= 1) {
        int y = __shfl_up(x, d2);
        if (lane >= d2) x += y;
    }
    if (lane == 63) wsum[wid] = x;
    __syncthreads();
    if (tid < 16) {
        int t = wsum[tid];
        #pragma unroll
        for (int d2 = 1; d2 < 16; d2 <<= 1) {
            int y = __shfl_up(t, d2, 16);
            if (tid >= d2) t += y;
        }
        wsum[tid] = t;
    }
    __syncthreads();
    int wbase = wid ? wsum[wid - 1] : 0;
    int pre = wbase + (x - s);                 // exclusive prefix within block
    if (i0 < n)     off[i0]     = pre;
    if (i0 + 1 < n) off[i0 + 1] = pre + v0;
    if (i0 + 2 < n) off[i0 + 2] = pre + v0 + v1;
    if (i0 + 3 < n) off[i0 + 3] = pre + v0 + v1 + v2;
    if (tid == 0) bsum[b] = wsum[15];          // block total
}

__global__ __launch_bounds__(1024) void scan3_kernel(int* __restrict__ off,
                                                     int* __restrict__ cur,
                                                     const int* __restrict__ bsum,
                                                     int n, int nb) {
    int b = blockIdx.x;
    int base = 0;
    for (int i = 0; i < b; ++i) base += bsum[i];   // <=12 uniform scalar loads
    int i = b * 4096 + threadIdx.x * 4;
    if (i + 3 < n) {
        int4 q = *(int4*)(off + i);
        q.x += base; q.y += base; q.z += base; q.w += base;
        *(int4*)(off + i) = q;
        *(int4*)(cur + i) = q;
    } else {
        #pragma unroll
        for (int k = 0; k < 4; ++k)
            if (i + k < n) {
                int v = off[i + k] + base;
                off[i + k] = v;
                cur[i + k] = v;
            }
    }
    if (b == nb - 1 && threadIdx.x == 0) off[n] = base + bsum[b];
}

// ------- scatter (CSR fill) and gemm1 fused into one launch (independent work) -------
// Blocks [0, nGb): gemm1 row-blocks. Blocks [nGb, nGb+nEb): scatter.
// gemm1: h1 = x @ W1 via MFMA + fused alpha dots; A staged once, B tiles restaged
// per col-block (L2/L3-resident). T2 swizzle on LDS granules.

__global__ __launch_bounds__(256) void gemm1_scatter_kernel(
        const float* __restrict__ x, const ushort* __restrict__ W1T,
        const float* __restrict__ a_src, const float* __restrict__ a_dst,
        uint32_t* __restrict__ h1, float* __restrict__ asrc1,
        float* __restrict__ adst1, int N, int nGb,
        const int* __restrict__ esrc, const int* __restrict__ edst,
        int* __restrict__ cur, int* __restrict__ csr_src, int E) {
    __shared__ __align__(16) ushort As[128][128];
    __shared__ __align__(16) ushort Bs[128][128];
    int tid = threadIdx.x;
    if ((int)blockIdx.x >= nGb) {   // ---- scatter branch (no barriers touched) ----
        int e = (blockIdx.x - nGb) * 256 + tid;
        if (e < E) {
            int d = edst[e];
            int p = atomicAdd(&cur[d], 1);
            csr_src[p] = esrc[e];
        }
        return;
    }
    int row0 = blockIdx.x * 128;

    {   // stage A (fp32 x -> bf16), swizzled — once
        int g = tid & 15;
        int r4 = tid >> 4;
        #pragma unroll
        for (int pass = 0; pass < 8; ++pass) {
            int r = r4 + pass * 16;
            int gr = row0 + r;
            float4 v0 = make_float4(0.f, 0.f, 0.f, 0.f), v1 = v0;
            if (gr < N) {
                v0 = *(const float4*)(x + (size_t)gr * 128 + g * 8);
                v1 = *(const float4*)(x + (size_t)gr * 128 + g * 8 + 4);
            }
            uint4 pk = make_uint4(pack_bf2(v0.x, v0.y), pack_bf2(v0.z, v0.w),
                                  pack_bf2(v1.x, v1.y), pack_bf2(v1.z, v1.w));
            *(uint4*)&As[r][(g ^ (r & 7)) * 8] = pk;
        }
    }
    __syncthreads();

    int wave = tid >> 6, lane = tid & 63;
    int wr = wave >> 1, wc = wave & 1;
    int lg = lane >> 4, lr = lane & 15;

    for (int cb = 0; cb < 4; ++cb) {
        int c0 = cb * 128;
        {   // stage B tile for this col-block
            int g = tid & 15;
            int r4 = tid >> 4;
            #pragma unroll
            for (int pass = 0; pass < 8; ++pass) {
                int r = r4 + pass * 16;
                uint4 q = *(const uint4*)(W1T + (size_t)(c0 + r) * 128 + g * 8);
                *(uint4*)&Bs[r][(g ^ (r & 7)) * 8] = q;
            }
        }
        __syncthreads();

        f32x4 acc[4][4] = {};
        #pragma unroll
        for (int kk = 0; kk < 4; ++kk) {
            bf16x8 a[4], b[4];
            int gk = kk * 4 + lg;
            #pragma unroll
            for (int mi = 0; mi < 4; ++mi) {
                int r = wr * 64 + mi * 16 + lr;
                a[mi] = *(const bf16x8*)&As[r][(gk ^ (r & 7)) * 8];
            }
            #pragma unroll
            for (int nj = 0; nj < 4; ++nj) {
                int r = wc * 64 + nj * 16 + lr;
                b[nj] = *(const bf16x8*)&Bs[r][(gk ^ (r & 7)) * 8];
            }
            #pragma unroll
            for (int mi = 0; mi < 4; ++mi)
                #pragma unroll
                for (int nj = 0; nj < 4; ++nj)
                    acc[mi][nj] = __builtin_amdgcn_mfma_f32_16x16x32_bf16(
                        a[mi], b[nj], acc[mi][nj], 0, 0, 0);
        }

        // ---- epilogue: alpha dots + bf16 pack. D mapping: col=lr, row=lg*4+reg.
        int hh = cb * 2 + wc;  // head for this wave's 64 cols
        float as4[4], ad4[4];
        #pragma unroll
        for (int nj = 0; nj < 4; ++nj) {
            as4[nj] = a_src[hh * 64 + nj * 16 + lr];
            ad4[nj] = a_dst[hh * 64 + nj * 16 + lr];
        }
        #pragma unroll
        for (int mi = 0; mi < 4; ++mi) {
            #pragma unroll
            for (int reg = 0; reg < 4; ++reg) {
                int row = row0 + wr * 64 + mi * 16 + lg * 4 + reg;
                float v0 = acc[mi][0][reg], v1 = acc[mi][1][reg];
                float v2 = acc[mi][2][reg], v3 = acc[mi][3][reg];
                float ps = v0 * as4[0] + v1 * as4[1] + v2 * as4[2] + v3 * as4[3];
                float pd = v0 * ad4[0] + v1 * ad4[1] + v2 * ad4[2] + v3 * ad4[3];
                #pragma unroll
                for (int m = 1; m < 16; m <<= 1) {
                    ps += __shfl_xor(ps, m);
                    pd += __shfl_xor(pd, m);
                }
                bool store_row = (row < N);
                if (store_row && lr == 0) {
                    asrc1[(size_t)row * 8 + hh] = ps;
                    adst1[(size_t)row * 8 + hh] = pd;
                }
                float p0 = __shfl_xor(v0, 1), p1 = __shfl_xor(v1, 1);
                float p2 = __shfl_xor(v2, 1), p3 = __shfl_xor(v3, 1);
                if (store_row && (lr & 1) == 0) {
                    size_t base = (size_t)row * 256 + ((c0 + wc * 64 + lr) >> 1);
                    h1[base + 0]  = pack_bf2(v0, p0);
                    h1[base + 8]  = pack_bf2(v1, p1);
                    h1[base + 16] = pack_bf2(v2, p2);
                    h1[base + 24] = pack_bf2(v3, p3);
                }
            }
        }
        __syncthreads();   // all waves done with Bs before restaging
    }
}

// ------- Fused layer-1 aggregation + layer-2 GEMM + alpha2 (one wave per node) -------
// Lane l owns contiguous channels [8l, 8l+8) (head = l>>3). W2 staged in LDS [64][68].

__global__ __launch_bounds__(256) void agg1_fused_kernel(
        const uint4* __restrict__ h1, const float* __restrict__ asrc,
        const float* __restrict__ adst, const int* __restrict__ off,
        const int* __restrict__ csr_src, const float* __restrict__ b1,
        const float* __restrict__ W2, const float* __restrict__ a_src2,
        const float* __restrict__ a_dst2, float* __restrict__ h2,
        float* __restrict__ as2, float* __restrict__ ad2, int N) {
    __shared__ __align__(16) float w2s[64 * 68];
    int tid = threadIdx.x;
    #pragma unroll
    for (int q = 0; q < 4; ++q) {
        float4 v = ((const float4*)W2)[tid * 4 + q];
        int g = tid * 16 + q * 4;               // global float index
        *(float4*)&w2s[(g >> 6) * 68 + (g & 63)] = v;
    }
    __syncthreads();

    int n = (blockIdx.x * blockDim.x + tid) >> 6;
    int lane = tid & 63;
    if (n >= N) return;  // after barrier: safe
    int hd = lane >> 3;
    float ad = adst[(size_t)n * 8 + hd];
    float2 acc2[4];
    float d;
    {   // self loop
        float w = __expf(LEAKY(asrc[(size_t)n * 8 + hd] + ad));
        d = w;
        uint4 p = h1[(size_t)n * 64 + lane];
        float2 c0 = bf2_to_f2(p.x), c1 = bf2_to_f2(p.y);
        float2 c2 = bf2_to_f2(p.z), c3 = bf2_to_f2(p.w);
        acc2[0] = make_float2(w * c0.x, w * c0.y);
        acc2[1] = make_float2(w * c1.x, w * c1.y);
        acc2[2] = make_float2(w * c2.x, w * c2.y);
        acc2[3] = make_float2(w * c3.x, w * c3.y);
    }
    auto addp = [&](uint4 p, float w) {
        float2 c0 = bf2_to_f2(p.x), c1 = bf2_to_f2(p.y);
        float2 c2 = bf2_to_f2(p.z), c3 = bf2_to_f2(p.w);
        d += w;
        acc2[0].x += w * c0.x; acc2[0].y += w * c0.y;
        acc2[1].x += w * c1.x; acc2[1].y += w * c1.y;
        acc2[2].x += w * c2.x; acc2[2].y += w * c2.y;
        acc2[3].x += w * c3.x; acc2[3].y += w * c3.y;
    };
    int t = off[n], tend = off[n + 1];
    for (; t + 3 < tend; t += 4) {
        int s0 = csr_src[t], s1 = csr_src[t + 1];
        int s2 = csr_src[t + 2], s3 = csr_src[t + 3];
        uint4 p0 = h1[(size_t)s0 * 64 + lane];
        uint4 p1 = h1[(size_t)s1 * 64 + lane];
        uint4 p2 = h1[(size_t)s2 * 64 + lane];
        uint4 p3 = h1[(size_t)s3 * 64 + lane];
        float w0 = __expf(LEAKY(asrc[(size_t)s0 * 8 + hd] + ad));
        float w1 = __expf(LEAKY(asrc[(size_t)s1 * 8 + hd] + ad));
        float w2 = __expf(LEAKY(asrc[(size_t)s2 * 8 + hd] + ad));
        float w3 = __expf(LEAKY(asrc[(size_t)s3 * 8 + hd] + ad));
        addp(p0, w0); addp(p1, w1); addp(p2, w2); addp(p3, w3);
    }
    for (; t < tend; ++t) {
        int s = csr_src[t];
        uint4 p = h1[(size_t)s * 64 + lane];
        float w = __expf(LEAKY(asrc[(size_t)s * 8 + hd] + ad));
        addp(p, w);
    }
    float inv = 1.f / (d + 1e-16f);
    float4 b0 = *(const float4*)(b1 + lane * 8);
    float4 b4 = *(const float4*)(b1 + lane * 8 + 4);
    float o[8];
    o[0] = fmaxf(acc2[0].x * inv + b0.x, 0.f);
    o[1] = fmaxf(acc2[0].y * inv + b0.y, 0.f);
    o[2] = fmaxf(acc2[1].x * inv + b0.z, 0.f);
    o[3] = fmaxf(acc2[1].y * inv + b0.w, 0.f);
    o[4] = fmaxf(acc2[2].x * inv + b4.x, 0.f);
    o[5] = fmaxf(acc2[2].y * inv + b4.y, 0.f);
    o[6] = fmaxf(acc2[3].x * inv + b4.z, 0.f);
    o[7] = fmaxf(acc2[3].y * inv + b4.w, 0.f);
    asm volatile("" ::: "memory");
    const float* wrow = &w2s[lane * 68];
    float pc[8] = {};
    #pragma unroll
    for (int j = 0; j < 8; ++j) {
        float4 wa = *(const float4*)(wrow + j * 8);
        float4 wb = *(const float4*)(wrow + j * 8 + 4);
        float ov = o[j];
        pc[0] += ov * wa.x; pc[1] += ov * wa.y;
        pc[2] += ov * wa.z; pc[3] += ov * wa.w;
        pc[4] += ov * wb.x; pc[5] += ov * wb.y;
        pc[6] += ov * wb.z; pc[7] += ov * wb.w;
    }
    #pragma unroll
    for (int m = 1; m < 64; m <<= 1)
        #pragma unroll
        for (int c = 0; c < 8; ++c)
            pc[c] += __shfl_xor(pc[c], m);
    if (lane < 8) {
        float myv = 0.f;
        #pragma unroll
        for (int c = 0; c < 8; ++c) if (lane == c) myv = pc[c];
        h2[(size_t)n * 8 + lane] = myv;
        if (lane == 0) {
            float pa = 0.f, pb = 0.f;
            #pragma unroll
            for (int c = 0; c < 8; ++c) { pa += pc[c] * a_src2[c]; pb += pc[c] * a_dst2[c]; }
            as2[n] = pa;
            ad2[n] = pb;
        }
    }
}

// ---------------- Layer 2 aggregation (8 lanes per node, 2-edge unroll) ----------------

__global__ __launch_bounds__(256) void agg2_kernel(const float* __restrict__ h2,
                                                   const float* __restrict__ as2,
                                                   const float* __restrict__ ad2,
                                                   const int* __restrict__ off,
                                                   const int* __restrict__ csr_src,
                                                   const float* __restrict__ b2,
                                                   float* __restrict__ out, int N) {
    int gid = blockIdx.x * blockDim.x + threadIdx.x;
    int n = gid >> 3, c = gid & 7;
    if (n >= N) return;
    float adn = ad2[n];
    float w = __expf(LEAKY(as2[n] + adn));
    float d = w;
    float acc = w * h2[(size_t)n * 8 + c];
    int t = off[n], tend = off[n + 1];
    for (; t + 1 < tend; t += 2) {
        int s0 = csr_src[t], s1 = csr_src[t + 1];
        float h0 = h2[(size_t)s0 * 8 + c];
        float h1v = h2[(size_t)s1 * 8 + c];
        float w0 = __expf(LEAKY(as2[s0] + adn));
        float w1 = __expf(LEAKY(as2[s1] + adn));
        d += w0 + w1;
        acc += w0 * h0 + w1 * h1v;
    }
    if (t < tend) {
        int s = csr_src[t];
        float ws = __expf(LEAKY(as2[s] + adn));
        d += ws;
        acc += ws * h2[(size_t)s * 8 + c];
    }
    out[(size_t)n * 8 + c] = acc / (d + 1e-16f) + b2[c];
}

// ---------------- launcher ----------------

extern "C" void kernel_launch(void* const* d_in, const int* in_sizes, int n_in,
                              void* d_out, int out_size, void* d_ws, size_t ws_size,
                              hipStream_t stream) {
    const float* x      = (const float*)d_in[0];
    const int*   ei     = (const int*)d_in[1];
    const float* W1     = (const float*)d_in[2];
    const float* a_src1 = (const float*)d_in[3];
    const float* a_dst1 = (const float*)d_in[4];
    const float* b1     = (const float*)d_in[5];
    const float* W2     = (const float*)d_in[6];
    const float* a_src2 = (const float*)d_in[7];
    const float* a_dst2 = (const float*)d_in[8];
    const float* b2     = (const float*)d_in[9];

    int N = in_sizes[0] / 128;
    int E = in_sizes[1] / 2;
    const int* src = ei;
    const int* dst = ei + E;

    char* w = (char*)d_ws;
    size_t o = 0;
    auto alloc = [&](size_t bytes) {
        void* p = w + o;
        o = (o + bytes + 255) & ~(size_t)255;
        return p;
    };
    uint32_t* h1     = (uint32_t*)alloc((size_t)N * 256 * 4);  // bf16 [N,512]
    float*    asrc1  = (float*)alloc((size_t)N * 8 * 4);
    float*    adst1  = (float*)alloc((size_t)N * 8 * 4);
    float*    h2     = (float*)alloc((size_t)N * 8 * 4);
    float*    as2    = (float*)alloc((size_t)N * 4);
    float*    ad2    = (float*)alloc((size_t)N * 4);
    int*      deg    = (int*)alloc((size_t)N * 4);
    int*      offb   = (int*)alloc((size_t)(N + 1) * 4);
    int*      cur    = (int*)alloc((size_t)N * 4);
    int*      csrs   = (int*)alloc((size_t)E * 4);
    ushort*   W1T    = (ushort*)alloc((size_t)512 * 128 * 2);
    int*      bsum   = (int*)alloc(64 * 4);

    hipMemsetAsync(deg, 0, (size_t)N * 4, stream);

    int nb = (N + 4095) / 4096;
    int nEb = (E + 255) / 256;
    int nGb = (N + 127) / 128;
    degree_w1t_kernel<<<nEb + 8, 256, 0, stream>>>(dst, deg, E, nEb, W1, W1T);
    scan1_kernel<<<nb, 1024, 0, stream>>>(deg, offb, bsum, N);
    scan3_kernel<<<nb, 1024, 0, stream>>>(offb, cur, bsum, N, nb);

    gemm1_scatter_kernel<<<nGb + nEb, 256, 0, stream>>>(
        x, W1T, a_src1, a_dst1, h1, asrc1, adst1, N, nGb,
        src, dst, cur, csrs, E);

    agg1_fused_kernel<<<((size_t)N * 64 + 255) / 256, 256, 0, stream>>>(
        (const uint4*)h1, asrc1, adst1, offb, csrs, b1, W2, a_src2, a_dst2,
        h2, as2, ad2, N);

    agg2_kernel<<<((size_t)N * 8 + 255) / 256, 256, 0, stream>>>(h2, as2, ad2, offb, csrs, b2,
                                                                 (float*)d_out, N);
}

// Round 18
// 168.948 us; speedup vs baseline: 1.0594x; 1.0076x over previous
//
#include <hip/hip_runtime.h>
#include <stdint.h>

#define LEAKY(x) fmaxf((x), 0.2f * (x))

typedef short bf16x8 __attribute__((ext_vector_type(8)));
typedef float f32x4 __attribute__((ext_vector_type(4)));

__device__ inline float2 bf2_to_f2(uint32_t p) {
    return make_float2(__uint_as_float(p << 16), __uint_as_float(p & 0xffff0000u));
}
__device__ inline uint32_t pack_bf2(float x, float y) {
    uint32_t xb = __float_as_uint(x), yb = __float_as_uint(y);
    xb += 0x7fff + ((xb >> 16) & 1);   // RNE to bf16
    yb += 0x7fff + ((yb >> 16) & 1);
    return (xb >> 16) | (yb & 0xffff0000u);
}
__device__ inline ushort to_bf16(float v) {
    uint32_t b = __float_as_uint(v);
    b += 0x7fff + ((b >> 16) & 1);
    return (ushort)(b >> 16);
}

// ------- CSR degree + (independent) W1 transpose fused into one launch -------

__global__ __launch_bounds__(256) void degree_w1t_kernel(const int* __restrict__ dst,
                                                         int* __restrict__ deg, int E,
                                                         int nEb,
                                                         const float* __restrict__ W,
                                                         ushort* __restrict__ WT) {
    if ((int)blockIdx.x < nEb) {
        int e = blockIdx.x * 256 + threadIdx.x;
        if (e < E) atomicAdd(&deg[dst[e]], 1);
    } else {
        int bb = blockIdx.x - nEb;                 // 0..7
        int c = bb * 64 + (threadIdx.x & 63);
        int k0 = (threadIdx.x >> 6) * 32;
        #pragma unroll
        for (int j = 0; j < 32; ++j)
            WT[(size_t)c * 128 + k0 + j] = to_bf16(W[(size_t)(k0 + j) * 512 + c]);
    }
}

// ------- Single-pass exclusive scan over 50K degrees (13 blocks, lookback) -------
// Each block scans its 4096-chunk, publishes total+1 to bflag[b] (atomicExch; the
// value itself carries the payload), and thread-0 spin-reads flags of preceding
// blocks (<=12, all co-resident on 256 CUs) to get its base. Emits off and cur.

__global__ __launch_bounds__(1024) void scan_fused_kernel(const int* __restrict__ deg,
                                                          int* __restrict__ off,
                                                          int* __restrict__ cur,
                                                          int* __restrict__ bflag,
                                                          int n, int nb) {
    __shared__ int wsum[16];
    __shared__ int sbase;
    int b = blockIdx.x, tid = threadIdx.x;
    int lane = tid & 63, wid = tid >> 6;
    int i0 = b * 4096 + tid * 4;
    int v0 = 0, v1 = 0, v2 = 0, v3 = 0;
    if (i0 + 3 < n) {
        int4 q = *(const int4*)(deg + i0);
        v0 = q.x; v1 = q.y; v2 = q.z; v3 = q.w;
    } else {
        if (i0 + 0 < n) v0 = deg[i0];
        if (i0 + 1 < n) v1 = deg[i0 + 1];
        if (i0 + 2 < n) v2 = deg[i0 + 2];
        if (i0 + 3 < n) v3 = deg[i0 + 3];
    }
    int s = v0 + v1 + v2 + v3;
    int x = s;
    #pragma unroll
    for (int d2 = 1; d2 < 64; d2 <<= 1) {
        int y = __shfl_up(x, d2);
        if (lane >= d2) x += y;
    }
    if (lane == 63) wsum[wid] = x;
    __syncthreads();
    if (tid < 16) {
        int t = wsum[tid];
        #pragma unroll
        for (int d2 = 1; d2 < 16; d2 <<= 1) {
            int y = __shfl_up(t, d2, 16);
            if (tid >= d2) t += y;
        }
        wsum[tid] = t;
    }
    __syncthreads();
    int wbase = wid ? wsum[wid - 1] : 0;
    int total = wsum[15];
    if (tid == 0) {
        atomicExch(&bflag[b], total + 1);          // publish (value = payload)
        int base = 0;
        for (int i = 0; i < b; ++i) {              // lookback over predecessors
            int v;
            while ((v = atomicAdd(&bflag[i], 0)) == 0) {}
            base += v - 1;
        }
        sbase = base;
    }
    __syncthreads();
    int base = sbase;
    int pre = base + wbase + (x - s);              // exclusive prefix (global)
    if (i0 + 3 < n) {
        int4 q = make_int4(pre, pre + v0, pre + v0 + v1, pre + v0 + v1 + v2);
        *(int4*)(off + i0) = q;
        *(int4*)(cur + i0) = q;
    } else {
        int p0 = pre, p1 = pre + v0, p2 = pre + v0 + v1, p3 = pre + v0 + v1 + v2;
        if (i0 + 0 < n) { off[i0] = p0; cur[i0] = p0; }
        if (i0 + 1 < n) { off[i0 + 1] = p1; cur[i0 + 1] = p1; }
        if (i0 + 2 < n) { off[i0 + 2] = p2; cur[i0 + 2] = p2; }
        if (i0 + 3 < n) { off[i0 + 3] = p3; cur[i0 + 3] = p3; }
    }
    if (b == nb - 1 && tid == 0) off[n] = base + total;
}

// ------- scatter (CSR fill) and gemm1 fused into one launch (independent work) -------
// Blocks [0, nGb): gemm1 row-blocks. Blocks [nGb, nGb+nEb): scatter.
// gemm1: h1 = x @ W1 via MFMA + fused alpha dots; A staged once, B tiles restaged
// per col-block (L2/L3-resident). T2 swizzle on LDS granules.

__global__ __launch_bounds__(256) void gemm1_scatter_kernel(
        const float* __restrict__ x, const ushort* __restrict__ W1T,
        const float* __restrict__ a_src, const float* __restrict__ a_dst,
        uint32_t* __restrict__ h1, float* __restrict__ asrc1,
        float* __restrict__ adst1, int N, int nGb,
        const int* __restrict__ esrc, const int* __restrict__ edst,
        int* __restrict__ cur, int* __restrict__ csr_src, int E) {
    __shared__ __align__(16) ushort As[128][128];
    __shared__ __align__(16) ushort Bs[128][128];
    int tid = threadIdx.x;
    if ((int)blockIdx.x >= nGb) {   // ---- scatter branch (no barriers touched) ----
        int e = (blockIdx.x - nGb) * 256 + tid;
        if (e < E) {
            int d = edst[e];
            int p = atomicAdd(&cur[d], 1);
            csr_src[p] = esrc[e];
        }
        return;
    }
    int row0 = blockIdx.x * 128;

    {   // stage A (fp32 x -> bf16), swizzled — once
        int g = tid & 15;
        int r4 = tid >> 4;
        #pragma unroll
        for (int pass = 0; pass < 8; ++pass) {
            int r = r4 + pass * 16;
            int gr = row0 + r;
            float4 v0 = make_float4(0.f, 0.f, 0.f, 0.f), v1 = v0;
            if (gr < N) {
                v0 = *(const float4*)(x + (size_t)gr * 128 + g * 8);
                v1 = *(const float4*)(x + (size_t)gr * 128 + g * 8 + 4);
            }
            uint4 pk = make_uint4(pack_bf2(v0.x, v0.y), pack_bf2(v0.z, v0.w),
                                  pack_bf2(v1.x, v1.y), pack_bf2(v1.z, v1.w));
            *(uint4*)&As[r][(g ^ (r & 7)) * 8] = pk;
        }
    }
    __syncthreads();

    int wave = tid >> 6, lane = tid & 63;
    int wr = wave >> 1, wc = wave & 1;
    int lg = lane >> 4, lr = lane & 15;

    for (int cb = 0; cb < 4; ++cb) {
        int c0 = cb * 128;
        {   // stage B tile for this col-block
            int g = tid & 15;
            int r4 = tid >> 4;
            #pragma unroll
            for (int pass = 0; pass < 8; ++pass) {
                int r = r4 + pass * 16;
                uint4 q = *(const uint4*)(W1T + (size_t)(c0 + r) * 128 + g * 8);
                *(uint4*)&Bs[r][(g ^ (r & 7)) * 8] = q;
            }
        }
        __syncthreads();

        f32x4 acc[4][4] = {};
        #pragma unroll
        for (int kk = 0; kk < 4; ++kk) {
            bf16x8 a[4], b[4];
            int gk = kk * 4 + lg;
            #pragma unroll
            for (int mi = 0; mi < 4; ++mi) {
                int r = wr * 64 + mi * 16 + lr;
                a[mi] = *(const bf16x8*)&As[r][(gk ^ (r & 7)) * 8];
            }
            #pragma unroll
            for (int nj = 0; nj < 4; ++nj) {
                int r = wc * 64 + nj * 16 + lr;
                b[nj] = *(const bf16x8*)&Bs[r][(gk ^ (r & 7)) * 8];
            }
            #pragma unroll
            for (int mi = 0; mi < 4; ++mi)
                #pragma unroll
                for (int nj = 0; nj < 4; ++nj)
                    acc[mi][nj] = __builtin_amdgcn_mfma_f32_16x16x32_bf16(
                        a[mi], b[nj], acc[mi][nj], 0, 0, 0);
        }

        // ---- epilogue: alpha dots + bf16 pack. D mapping: col=lr, row=lg*4+reg.
        int hh = cb * 2 + wc;  // head for this wave's 64 cols
        float as4[4], ad4[4];
        #pragma unroll
        for (int nj = 0; nj < 4; ++nj) {
            as4[nj] = a_src[hh * 64 + nj * 16 + lr];
            ad4[nj] = a_dst[hh * 64 + nj * 16 + lr];
        }
        #pragma unroll
        for (int mi = 0; mi < 4; ++mi) {
            #pragma unroll
            for (int reg = 0; reg < 4; ++reg) {
                int row = row0 + wr * 64 + mi * 16 + lg * 4 + reg;
                float v0 = acc[mi][0][reg], v1 = acc[mi][1][reg];
                float v2 = acc[mi][2][reg], v3 = acc[mi][3][reg];
                float ps = v0 * as4[0] + v1 * as4[1] + v2 * as4[2] + v3 * as4[3];
                float pd = v0 * ad4[0] + v1 * ad4[1] + v2 * ad4[2] + v3 * ad4[3];
                #pragma unroll
                for (int m = 1; m < 16; m <<= 1) {
                    ps += __shfl_xor(ps, m);
                    pd += __shfl_xor(pd, m);
                }
                bool store_row = (row < N);
                if (store_row && lr == 0) {
                    asrc1[(size_t)row * 8 + hh] = ps;
                    adst1[(size_t)row * 8 + hh] = pd;
                }
                float p0 = __shfl_xor(v0, 1), p1 = __shfl_xor(v1, 1);
                float p2 = __shfl_xor(v2, 1), p3 = __shfl_xor(v3, 1);
                if (store_row && (lr & 1) == 0) {
                    size_t base = (size_t)row * 256 + ((c0 + wc * 64 + lr) >> 1);
                    h1[base + 0]  = pack_bf2(v0, p0);
                    h1[base + 8]  = pack_bf2(v1, p1);
                    h1[base + 16] = pack_bf2(v2, p2);
                    h1[base + 24] = pack_bf2(v3, p3);
                }
            }
        }
        __syncthreads();   // all waves done with Bs before restaging
    }
}

// ------- Fused layer-1 aggregation + layer-2 GEMM + alpha2 (one wave per node) -------
// Lane l owns contiguous channels [8l, 8l+8) (head = l>>3). W2 staged in LDS [64][68].

__global__ __launch_bounds__(256) void agg1_fused_kernel(
        const uint4* __restrict__ h1, const float* __restrict__ asrc,
        const float* __restrict__ adst, const int* __restrict__ off,
        const int* __restrict__ csr_src, const float* __restrict__ b1,
        const float* __restrict__ W2, const float* __restrict__ a_src2,
        const float* __restrict__ a_dst2, float* __restrict__ h2,
        float* __restrict__ as2, float* __restrict__ ad2, int N) {
    __shared__ __align__(16) float w2s[64 * 68];
    int tid = threadIdx.x;
    #pragma unroll
    for (int q = 0; q < 4; ++q) {
        float4 v = ((const float4*)W2)[tid * 4 + q];
        int g = tid * 16 + q * 4;               // global float index
        *(float4*)&w2s[(g >> 6) * 68 + (g & 63)] = v;
    }
    __syncthreads();

    int n = (blockIdx.x * blockDim.x + tid) >> 6;
    int lane = tid & 63;
    if (n >= N) return;  // after barrier: safe
    int hd = lane >> 3;
    float ad = adst[(size_t)n * 8 + hd];
    float2 acc2[4];
    float d;
    {   // self loop
        float w = __expf(LEAKY(asrc[(size_t)n * 8 + hd] + ad));
        d = w;
        uint4 p = h1[(size_t)n * 64 + lane];
        float2 c0 = bf2_to_f2(p.x), c1 = bf2_to_f2(p.y);
        float2 c2 = bf2_to_f2(p.z), c3 = bf2_to_f2(p.w);
        acc2[0] = make_float2(w * c0.x, w * c0.y);
        acc2[1] = make_float2(w * c1.x, w * c1.y);
        acc2[2] = make_float2(w * c2.x, w * c2.y);
        acc2[3] = make_float2(w * c3.x, w * c3.y);
    }
    auto addp = [&](uint4 p, float w) {
        float2 c0 = bf2_to_f2(p.x), c1 = bf2_to_f2(p.y);
        float2 c2 = bf2_to_f2(p.z), c3 = bf2_to_f2(p.w);
        d += w;
        acc2[0].x += w * c0.x; acc2[0].y += w * c0.y;
        acc2[1].x += w * c1.x; acc2[1].y += w * c1.y;
        acc2[2].x += w * c2.x; acc2[2].y += w * c2.y;
        acc2[3].x += w * c3.x; acc2[3].y += w * c3.y;
    };
    int t = off[n], tend = off[n + 1];
    for (; t + 3 < tend; t += 4) {
        int s0 = csr_src[t], s1 = csr_src[t + 1];
        int s2 = csr_src[t + 2], s3 = csr_src[t + 3];
        uint4 p0 = h1[(size_t)s0 * 64 + lane];
        uint4 p1 = h1[(size_t)s1 * 64 + lane];
        uint4 p2 = h1[(size_t)s2 * 64 + lane];
        uint4 p3 = h1[(size_t)s3 * 64 + lane];
        float w0 = __expf(LEAKY(asrc[(size_t)s0 * 8 + hd] + ad));
        float w1 = __expf(LEAKY(asrc[(size_t)s1 * 8 + hd] + ad));
        float w2 = __expf(LEAKY(asrc[(size_t)s2 * 8 + hd] + ad));
        float w3 = __expf(LEAKY(asrc[(size_t)s3 * 8 + hd] + ad));
        addp(p0, w0); addp(p1, w1); addp(p2, w2); addp(p3, w3);
    }
    for (; t < tend; ++t) {
        int s = csr_src[t];
        uint4 p = h1[(size_t)s * 64 + lane];
        float w = __expf(LEAKY(asrc[(size_t)s * 8 + hd] + ad));
        addp(p, w);
    }
    float inv = 1.f / (d + 1e-16f);
    float4 b0 = *(const float4*)(b1 + lane * 8);
    float4 b4 = *(const float4*)(b1 + lane * 8 + 4);
    float o[8];
    o[0] = fmaxf(acc2[0].x * inv + b0.x, 0.f);
    o[1] = fmaxf(acc2[0].y * inv + b0.y, 0.f);
    o[2] = fmaxf(acc2[1].x * inv + b0.z, 0.f);
    o[3] = fmaxf(acc2[1].y * inv + b0.w, 0.f);
    o[4] = fmaxf(acc2[2].x * inv + b4.x, 0.f);
    o[5] = fmaxf(acc2[2].y * inv + b4.y, 0.f);
    o[6] = fmaxf(acc2[3].x * inv + b4.z, 0.f);
    o[7] = fmaxf(acc2[3].y * inv + b4.w, 0.f);
    asm volatile("" ::: "memory");
    const float* wrow = &w2s[lane * 68];
    float pc[8] = {};
    #pragma unroll
    for (int j = 0; j < 8; ++j) {
        float4 wa = *(const float4*)(wrow + j * 8);
        float4 wb = *(const float4*)(wrow + j * 8 + 4);
        float ov = o[j];
        pc[0] += ov * wa.x; pc[1] += ov * wa.y;
        pc[2] += ov * wa.z; pc[3] += ov * wa.w;
        pc[4] += ov * wb.x; pc[5] += ov * wb.y;
        pc[6] += ov * wb.z; pc[7] += ov * wb.w;
    }
    #pragma unroll
    for (int m = 1; m < 64; m <<= 1)
        #pragma unroll
        for (int c = 0; c < 8; ++c)
            pc[c] += __shfl_xor(pc[c], m);
    if (lane < 8) {
        float myv = 0.f;
        #pragma unroll
        for (int c = 0; c < 8; ++c) if (lane == c) myv = pc[c];
        h2[(size_t)n * 8 + lane] = myv;
        if (lane == 0) {
            float pa = 0.f, pb = 0.f;
            #pragma unroll
            for (int c = 0; c < 8; ++c) { pa += pc[c] * a_src2[c]; pb += pc[c] * a_dst2[c]; }
            as2[n] = pa;
            ad2[n] = pb;
        }
    }
}

// ---------------- Layer 2 aggregation (8 lanes per node, 2-edge unroll) ----------------

__global__ __launch_bounds__(256) void agg2_kernel(const float* __restrict__ h2,
                                                   const float* __restrict__ as2,
                                                   const float* __restrict__ ad2,
                                                   const int* __restrict__ off,
                                                   const int* __restrict__ csr_src,
                                                   const float* __restrict__ b2,
                                                   float* __restrict__ out, int N) {
    int gid = blockIdx.x * blockDim.x + threadIdx.x;
    int n = gid >> 3, c = gid & 7;
    if (n >= N) return;
    float adn = ad2[n];
    float w = __expf(LEAKY(as2[n] + adn));
    float d = w;
    float acc = w * h2[(size_t)n * 8 + c];
    int t = off[n], tend = off[n + 1];
    for (; t + 1 < tend; t += 2) {
        int s0 = csr_src[t], s1 = csr_src[t + 1];
        float h0 = h2[(size_t)s0 * 8 + c];
        float h1v = h2[(size_t)s1 * 8 + c];
        float w0 = __expf(LEAKY(as2[s0] + adn));
        float w1 = __expf(LEAKY(as2[s1] + adn));
        d += w0 + w1;
        acc += w0 * h0 + w1 * h1v;
    }
    if (t < tend) {
        int s = csr_src[t];
        float ws = __expf(LEAKY(as2[s] + adn));
        d += ws;
        acc += ws * h2[(size_t)s * 8 + c];
    }
    out[(size_t)n * 8 + c] = acc / (d + 1e-16f) + b2[c];
}

// ---------------- launcher ----------------

extern "C" void kernel_launch(void* const* d_in, const int* in_sizes, int n_in,
                              void* d_out, int out_size, void* d_ws, size_t ws_size,
                              hipStream_t stream) {
    const float* x      = (const float*)d_in[0];
    const int*   ei     = (const int*)d_in[1];
    const float* W1     = (const float*)d_in[2];
    const float* a_src1 = (const float*)d_in[3];
    const float* a_dst1 = (const float*)d_in[4];
    const float* b1     = (const float*)d_in[5];
    const float* W2     = (const float*)d_in[6];
    const float* a_src2 = (const float*)d_in[7];
    const float* a_dst2 = (const float*)d_in[8];
    const float* b2     = (const float*)d_in[9];

    int N = in_sizes[0] / 128;
    int E = in_sizes[1] / 2;
    const int* src = ei;
    const int* dst = ei + E;

    char* w = (char*)d_ws;
    size_t o = 0;
    auto alloc = [&](size_t bytes) {
        void* p = w + o;
        o = (o + bytes + 255) & ~(size_t)255;
        return p;
    };
    uint32_t* h1     = (uint32_t*)alloc((size_t)N * 256 * 4);  // bf16 [N,512]
    float*    asrc1  = (float*)alloc((size_t)N * 8 * 4);
    float*    adst1  = (float*)alloc((size_t)N * 8 * 4);
    float*    h2     = (float*)alloc((size_t)N * 8 * 4);
    float*    as2    = (float*)alloc((size_t)N * 4);
    float*    ad2    = (float*)alloc((size_t)N * 4);
    int*      deg    = (int*)alloc((size_t)N * 4);   // deg + bflag zeroed together
    int*      bflag  = (int*)alloc(64 * 4);
    int*      offb   = (int*)alloc((size_t)(N + 1) * 4);
    int*      cur    = (int*)alloc((size_t)N * 4);
    int*      csrs   = (int*)alloc((size_t)E * 4);
    ushort*   W1T    = (ushort*)alloc((size_t)512 * 128 * 2);

    // deg and bflag are adjacent (alloc order): one memset covers both.
    size_t zero_bytes = ((size_t)N * 4 + 255 & ~(size_t)255) + 64 * 4;
    hipMemsetAsync(deg, 0, zero_bytes, stream);

    int nb = (N + 4095) / 4096;
    int nEb = (E + 255) / 256;
    int nGb = (N + 127) / 128;
    degree_w1t_kernel<<<nEb + 8, 256, 0, stream>>>(dst, deg, E, nEb, W1, W1T);
    scan_fused_kernel<<<nb, 1024, 0, stream>>>(deg, offb, cur, bflag, N, nb);

    gemm1_scatter_kernel<<<nGb + nEb, 256, 0, stream>>>(
        x, W1T, a_src1, a_dst1, h1, asrc1, adst1, N, nGb,
        src, dst, cur, csrs, E);

    agg1_fused_kernel<<<((size_t)N * 64 + 255) / 256, 256, 0, stream>>>(
        (const uint4*)h1, asrc1, adst1, offb, csrs, b1, W2, a_src2, a_dst2,
        h2, as2, ad2, N);

    agg2_kernel<<<((size_t)N * 8 + 255) / 256, 256, 0, stream>>>(h2, as2, ad2, offb, csrs, b2,
                                                                 (float*)d_out, N);
}